// Round 11
// baseline (300.529 us; speedup 1.0000x reference)
//
#include <hip/hip_runtime.h>
#include <hip/hip_bf16.h>
#include <cstdint>

#define N_NODES 10000
#define N_EDGES 160000
#define DIM 512
#define K1 1024
#define NEXP 4

typedef __bf16 bf16_t;
typedef bf16_t bf16x8 __attribute__((ext_vector_type(8)));
typedef float f32x4 __attribute__((ext_vector_type(4)));

#define AS1(p) ((__attribute__((address_space(1))) void*)(p))
#define AS3(p) ((__attribute__((address_space(3))) void*)(p))

// ---------------- zero counters ----------------
__global__ void zero_kernel(int* __restrict__ deg, int* __restrict__ ecnt) {
    int i = blockIdx.x * blockDim.x + threadIdx.x;
    if (i < N_NODES) deg[i] = 0;
    if (i < NEXP) ecnt[i] = 0;
}

// ---------------- gating + x->bf16 (no atomics) ----------------
__global__ void gate_kernel(const float* __restrict__ x,
                            const float* __restrict__ gw,
                            const float* __restrict__ gb,
                            int* __restrict__ top_idx,
                            float* __restrict__ top_val,
                            bf16_t* __restrict__ acat) {
    const int wave = threadIdx.x >> 6;
    const int lane = threadIdx.x & 63;
    const int node = blockIdx.x * 4 + wave;
    if (node >= N_NODES) return;
    const float4* x4 = (const float4*)(x + (size_t)node * DIM);
    const float4* gw4 = (const float4*)gw;
    float4 xa = x4[lane * 2];
    float4 xb = x4[lane * 2 + 1];
    float xv[8] = { xa.x, xa.y, xa.z, xa.w, xb.x, xb.y, xb.z, xb.w };
    float a0 = 0.f, a1 = 0.f, a2 = 0.f, a3 = 0.f;
    #pragma unroll
    for (int c = 0; c < 8; c++) {
        float4 g = gw4[lane * 8 + c];
        a0 += xv[c] * g.x; a1 += xv[c] * g.y; a2 += xv[c] * g.z; a3 += xv[c] * g.w;
    }
    bf16x8 o;
    #pragma unroll
    for (int c = 0; c < 8; c++) o[c] = (bf16_t)xv[c];
    *(bf16x8*)(acat + (size_t)node * K1 + DIM + lane * 8) = o;
    for (int off = 32; off > 0; off >>= 1) {
        a0 += __shfl_xor(a0, off);
        a1 += __shfl_xor(a1, off);
        a2 += __shfl_xor(a2, off);
        a3 += __shfl_xor(a3, off);
    }
    if (lane == 0) {
        float z[4] = { a0 + gb[0], a1 + gb[1], a2 + gb[2], a3 + gb[3] };
        int bi = 0; float bm = z[0];
        for (int e = 1; e < 4; e++) if (z[e] > bm) { bm = z[e]; bi = e; }
        float den = 0.f;
        for (int e = 0; e < 4; e++) den += expf(z[e] - bm);
        top_idx[node] = bi;
        top_val[node] = 1.0f / den;
    }
}

// ---------------- expert bucketing ----------------
__global__ void bucket_kernel(const int* __restrict__ top_idx,
                              int* __restrict__ ecnt,
                              int* __restrict__ lists) {
    __shared__ int lcnt[NEXP];
    __shared__ int base[NEXP];
    const int tid = threadIdx.x;
    if (tid < NEXP) lcnt[tid] = 0;
    __syncthreads();
    const int node = blockIdx.x * 256 + tid;
    int e = 0, rank = 0;
    if (node < N_NODES) {
        e = top_idx[node];
        rank = atomicAdd(&lcnt[e], 1);
    }
    __syncthreads();
    if (tid < NEXP) base[tid] = atomicAdd(&ecnt[tid], lcnt[tid]);
    __syncthreads();
    if (node < N_NODES) lists[e * N_NODES + base[e] + rank] = node;
}

// ---------------- CSR build ----------------
__global__ void deg_kernel(const int* __restrict__ dst, int* __restrict__ deg) {
    int i = blockIdx.x * blockDim.x + threadIdx.x;
    if (i < N_EDGES) atomicAdd(&deg[dst[i]], 1);
}

__global__ void scan_kernel(const int* __restrict__ deg,
                            int* __restrict__ offs,
                            int* __restrict__ cursor) {
    __shared__ int wsum[16];
    __shared__ int carrysh;
    const int tid = threadIdx.x;
    const int lane = tid & 63;
    const int wv = tid >> 6;
    if (tid == 0) carrysh = 0;
    __syncthreads();
    for (int base = 0; base < N_NODES; base += 1024) {
        int i = base + tid;
        int v = (i < N_NODES) ? deg[i] : 0;
        int s = v;
        #pragma unroll
        for (int off = 1; off < 64; off <<= 1) {
            int t = __shfl_up(s, off);
            if (lane >= off) s += t;
        }
        if (lane == 63) wsum[wv] = s;
        int carry = carrysh;
        __syncthreads();
        if (wv == 0) {
            int w = (lane < 16) ? wsum[lane] : 0;
            #pragma unroll
            for (int off = 1; off < 16; off <<= 1) {
                int t = __shfl_up(w, off);
                if (lane >= off) w += t;
            }
            if (lane < 16) wsum[lane] = w;
        }
        __syncthreads();
        int wbase = (wv > 0) ? wsum[wv - 1] : 0;
        int excl = carry + wbase + s - v;
        if (i < N_NODES) { offs[i] = excl; cursor[i] = excl; }
        int total = wsum[15];
        __syncthreads();
        if (tid == 0) carrysh = carry + total;
        __syncthreads();
    }
    if (tid == 0) offs[N_NODES] = carrysh;
}

__global__ void fill_kernel(const int* __restrict__ src, const int* __restrict__ dst,
                            int* __restrict__ cursor, int* __restrict__ csr) {
    int i = blockIdx.x * blockDim.x + threadIdx.x;
    if (i < N_EDGES) {
        int d = dst[i];
        int p = atomicAdd(&cursor[d], 1);
        csr[p] = src[i];
    }
}

// ---------------- weight convert+transpose ----------------
__global__ void wtrans_kernel(const float* __restrict__ w_neigh,
                              const float* __restrict__ w_self,
                              bf16_t* __restrict__ Bt) {
    __shared__ float tile[32][33];
    const int m = blockIdx.z;
    const bool isSelf = m >= 8;
    const int el = m & 7;
    const float* W = (isSelf ? w_self : w_neigh) + (size_t)el * DIM * DIM;
    const int k0 = blockIdx.x * 32;
    const int n0 = blockIdx.y * 32;
    const int tx = threadIdx.x, ty = threadIdx.y;
    for (int r = ty; r < 32; r += 8)
        tile[r][tx] = W[(size_t)(k0 + r) * DIM + n0 + tx];
    __syncthreads();
    for (int r = ty; r < 32; r += 8) {
        int n = n0 + r;
        int k = k0 + tx;
        Bt[((size_t)el * DIM + n) * K1 + (isSelf ? DIM : 0) + k] = (bf16_t)tile[tx][r];
    }
}

// ---------------- agg1: mean of x rows into acat cols 0..511, unroll 8 ----------------
__global__ void agg1_kernel(const int* __restrict__ offs, const int* __restrict__ csr,
                            bf16_t* __restrict__ acat) {
    const int wave = threadIdx.x >> 6;
    const int lane = threadIdx.x & 63;
    const int node = blockIdx.x * 4 + wave;
    if (node >= N_NODES) return;
    const int c0 = lane * 8;
    float s[8] = {0,0,0,0,0,0,0,0};
    int beg = offs[node];
    int end = offs[node + 1];
    int d = end - beg;
    int p = beg;
    for (; p + 8 <= end; p += 8) {
        bf16x8 v[8];
        #pragma unroll
        for (int q = 0; q < 8; q++) {
            int idx = csr[p + q];
            v[q] = *(const bf16x8*)(acat + (size_t)idx * K1 + DIM + c0);
        }
        #pragma unroll
        for (int q = 0; q < 8; q++)
            #pragma unroll
            for (int k = 0; k < 8; k++) s[k] += (float)v[q][k];
    }
    for (; p + 4 <= end; p += 4) {
        bf16x8 v[4];
        #pragma unroll
        for (int q = 0; q < 4; q++) {
            int idx = csr[p + q];
            v[q] = *(const bf16x8*)(acat + (size_t)idx * K1 + DIM + c0);
        }
        #pragma unroll
        for (int q = 0; q < 4; q++)
            #pragma unroll
            for (int k = 0; k < 8; k++) s[k] += (float)v[q][k];
    }
    for (; p < end; p++) {
        int idx = csr[p];
        bf16x8 v0 = *(const bf16x8*)(acat + (size_t)idx * K1 + DIM + c0);
        #pragma unroll
        for (int k = 0; k < 8; k++) s[k] += (float)v0[k];
    }
    float w = d > 0 ? 1.0f / (float)d : 0.0f;
    bf16x8 o;
    #pragma unroll
    for (int k = 0; k < 8; k++) o[k] = (bf16_t)(s[k] * w);
    *(bf16x8*)(acat + (size_t)node * K1 + c0) = o;
}

// ---------------- agg2: selected-expert mean of h1 rows + self copy, unroll 8 ----------------
__global__ void agg2_kernel(const int* __restrict__ offs, const int* __restrict__ csr,
                            const int* __restrict__ top_idx,
                            const bf16_t* __restrict__ h1, bf16_t* __restrict__ acat) {
    const int wave = threadIdx.x >> 6;
    const int lane = threadIdx.x & 63;
    const int node = blockIdx.x * 4 + wave;
    if (node >= N_NODES) return;
    const int c0 = lane * 8;
    const bf16_t* hb = h1 + (size_t)top_idx[node] * N_NODES * DIM;
    float s[8] = {0,0,0,0,0,0,0,0};
    int beg = offs[node];
    int end = offs[node + 1];
    int d = end - beg;
    int p = beg;
    for (; p + 8 <= end; p += 8) {
        bf16x8 v[8];
        #pragma unroll
        for (int q = 0; q < 8; q++) {
            int idx = csr[p + q];
            v[q] = *(const bf16x8*)(hb + (size_t)idx * DIM + c0);
        }
        #pragma unroll
        for (int q = 0; q < 8; q++)
            #pragma unroll
            for (int k = 0; k < 8; k++) s[k] += (float)v[q][k];
    }
    for (; p + 4 <= end; p += 4) {
        bf16x8 v[4];
        #pragma unroll
        for (int q = 0; q < 4; q++) {
            int idx = csr[p + q];
            v[q] = *(const bf16x8*)(hb + (size_t)idx * DIM + c0);
        }
        #pragma unroll
        for (int q = 0; q < 4; q++)
            #pragma unroll
            for (int k = 0; k < 8; k++) s[k] += (float)v[q][k];
    }
    for (; p < end; p++) {
        int idx = csr[p];
        bf16x8 v0 = *(const bf16x8*)(hb + (size_t)idx * DIM + c0);
        #pragma unroll
        for (int k = 0; k < 8; k++) s[k] += (float)v0[k];
    }
    float w = d > 0 ? 1.0f / (float)d : 0.0f;
    bf16x8 o;
    #pragma unroll
    for (int k = 0; k < 8; k++) o[k] = (bf16_t)(s[k] * w);
    *(bf16x8*)(acat + (size_t)node * K1 + c0) = o;
    *(bf16x8*)(acat + (size_t)node * K1 + DIM + c0) = *(const bf16x8*)(hb + (size_t)node * DIM + c0);
}

// ---------------- GEMM layer 1: 128x64 tiles for 8 blocks/CU, BK=32, swizzle, XCD-clustered ----------------
// grid 2560: xcd=b&7 -> (expert-pair, y-quarter); r=b>>3: yloc(20) x [bx(8) x e-in-pair(2)].
// LDS 12 KB (A 8 + B 4); acc[4][2]=32 VGPR; __launch_bounds__(256,8) targets 8 waves/SIMD.
// Wave (wm=wave&1, wn=wave>>1) computes rows [wm*64,+64) x cols [wn*32,+32): af[4], bfr[2], 8 MFMA.
__global__ __launch_bounds__(256, 8)
void gemm1_kernel(const bf16_t* __restrict__ A,
                  const bf16_t* __restrict__ Bt,
                  const float* __restrict__ bias_all,
                  bf16_t* __restrict__ h1) {
    const int b = blockIdx.x;
    const int xcd = b & 7;
    const int ke = xcd >> 2;
    const int ky = xcd & 3;
    const int r = b >> 3;          // 0..319
    const int yloc = r >> 4;       // 0..19
    const int xz = r & 15;
    const int bx = xz & 7;         // 0..7 (64-col tile)
    const int e = ke * 2 + (xz >> 3);
    const int by = ky * 20 + yloc;
    if (by >= 79) return;

    __shared__ __align__(16) bf16_t As[128 * 32];   // 8 KB
    __shared__ __align__(16) bf16_t Bs[64 * 32];    // 4 KB

    const int t = threadIdx.x;
    const int lane = t & 63;
    const int wave = t >> 6;
    const int wm = wave & 1;
    const int wn = wave >> 1;

    const int r0 = t >> 2;               // 0..63
    const int rot = (t >> 3) & 3;
    const int cgl = ((t & 3) - rot) & 3;

    int i0 = by * 128 + r0;
    int i1 = i0 + 64;
    int arow0 = min(i0, N_NODES - 1);
    int arow1 = min(i1, N_NODES - 1);

    const bf16_t* Bte = Bt + (size_t)(e * 2) * DIM * K1;   // layer 0
    const bf16_t* aptr0 = A + (size_t)arow0 * K1 + cgl * 8;
    const bf16_t* aptr1 = A + (size_t)arow1 * K1 + cgl * 8;
    const bf16_t* bptr0 = Bte + (size_t)(bx * 64 + r0) * K1 + cgl * 8;

    f32x4 acc[4][2] = {};
    char* asb = (char*)&As[0];
    char* bsb = (char*)&Bs[0];
    const int wb = wave * 1024;

    const int cpr = lane >> 4;
    const int rfr = lane & 15;

    for (int k0 = 0; k0 < K1; k0 += 32) {
        __syncthreads();
        __builtin_amdgcn_global_load_lds(AS1(aptr0), AS3(asb + wb),        16, 0, 0);
        __builtin_amdgcn_global_load_lds(AS1(aptr1), AS3(asb + 4096 + wb), 16, 0, 0);
        __builtin_amdgcn_global_load_lds(AS1(bptr0), AS3(bsb + wb),        16, 0, 0);
        __syncthreads();
        bf16x8 af[4], bfr[2];
        #pragma unroll
        for (int i = 0; i < 4; i++) {
            int rf = wm * 64 + i * 16 + rfr;
            int pp = (cpr + (rf >> 1)) & 3;
            af[i] = *(const bf16x8*)(As + rf * 32 + pp * 8);
        }
        #pragma unroll
        for (int j = 0; j < 2; j++) {
            int rf = wn * 32 + j * 16 + rfr;
            int pp = (cpr + (rf >> 1)) & 3;
            bfr[j] = *(const bf16x8*)(Bs + rf * 32 + pp * 8);
        }
        #pragma unroll
        for (int i = 0; i < 4; i++)
            #pragma unroll
            for (int j = 0; j < 2; j++)
                acc[i][j] = __builtin_amdgcn_mfma_f32_16x16x32_bf16(af[i], bfr[j], acc[i][j], 0, 0, 0);
        aptr0 += 32; aptr1 += 32; bptr0 += 32;
    }

    const float* bias = bias_all + e * 1024;   // layer 0
    const int cbase = bx * 64 + wn * 32 + (lane & 15);
    float bv[2];
    #pragma unroll
    for (int j = 0; j < 2; j++) bv[j] = bias[cbase + j * 16];
    #pragma unroll
    for (int i = 0; i < 4; i++) {
        #pragma unroll
        for (int rr = 0; rr < 4; rr++) {
            int row = by * 128 + wm * 64 + i * 16 + (lane >> 4) * 4 + rr;
            if (row < N_NODES) {
                bf16_t* cp = h1 + ((size_t)e * N_NODES + row) * DIM + cbase;
                #pragma unroll
                for (int j = 0; j < 2; j++) {
                    float v = fmaxf(acc[i][j][rr] + bv[j], 0.f);
                    cp[j * 16] = (bf16_t)v;
                }
            }
        }
    }
}

// ---------------- GEMM layer 2: 64x128 tiles, gathered rows (round-9 single-buffer) ----------------
__global__ __launch_bounds__(256)
void gemm2_kernel(const bf16_t* __restrict__ A,
                  const bf16_t* __restrict__ Bt,
                  const float* __restrict__ bias_all,
                  float* __restrict__ out,
                  const int* __restrict__ lists,
                  const int* __restrict__ ecnt,
                  const float* __restrict__ top_val) {
    const int bx = blockIdx.x, by = blockIdx.y, e = blockIdx.z;
    const int cnt = ecnt[e];
    if (by * 64 >= cnt) return;

    __shared__ __align__(16) bf16_t As[64 * 32];
    __shared__ __align__(16) bf16_t Bs[128 * 32];

    const int t = threadIdx.x;
    const int lane = t & 63;
    const int wave = t >> 6;

    const int r0 = t >> 2;
    const int rot = (t >> 3) & 3;
    const int cgl = ((t & 3) - rot) & 3;

    int i0 = by * 64 + r0;
    int arow0 = lists[e * N_NODES + min(i0, cnt - 1)];

    const bf16_t* Bte = Bt + (size_t)(e * 2 + 1) * DIM * K1;   // layer 1
    const bf16_t* aptr0 = A + (size_t)arow0 * K1 + cgl * 8;
    const bf16_t* bptr0 = Bte + (size_t)(bx * 128 + r0) * K1 + cgl * 8;
    const bf16_t* bptr1 = bptr0 + (size_t)64 * K1;

    f32x4 acc[4][2] = {};
    char* asb = (char*)&As[0];
    char* bsb = (char*)&Bs[0];
    const int wb = wave * 1024;

    const int cpr = lane >> 4;
    const int rfr = lane & 15;

    for (int k0 = 0; k0 < K1; k0 += 32) {
        __syncthreads();
        __builtin_amdgcn_global_load_lds(AS1(aptr0), AS3(asb + wb),        16, 0, 0);
        __builtin_amdgcn_global_load_lds(AS1(bptr0), AS3(bsb + wb),        16, 0, 0);
        __builtin_amdgcn_global_load_lds(AS1(bptr1), AS3(bsb + 4096 + wb), 16, 0, 0);
        __syncthreads();
        bf16x8 af[4], bfr[2];
        #pragma unroll
        for (int i = 0; i < 4; i++) {
            int rf = i * 16 + rfr;
            int pp = (cpr + (rf >> 1)) & 3;
            af[i] = *(const bf16x8*)(As + rf * 32 + pp * 8);
        }
        #pragma unroll
        for (int j = 0; j < 2; j++) {
            int rf = wave * 32 + j * 16 + rfr;
            int pp = (cpr + (rf >> 1)) & 3;
            bfr[j] = *(const bf16x8*)(Bs + rf * 32 + pp * 8);
        }
        #pragma unroll
        for (int i = 0; i < 4; i++)
            #pragma unroll
            for (int j = 0; j < 2; j++)
                acc[i][j] = __builtin_amdgcn_mfma_f32_16x16x32_bf16(af[i], bfr[j], acc[i][j], 0, 0, 0);
        aptr0 += 32; bptr0 += 32; bptr1 += 32;
    }

    const float* bias = bias_all + e * 1024 + DIM;   // layer 1
    const int cbase = bx * 128 + wave * 32 + (lane & 15);
    float bv[2];
    #pragma unroll
    for (int j = 0; j < 2; j++) bv[j] = bias[cbase + j * 16];
    #pragma unroll
    for (int i = 0; i < 4; i++) {
        #pragma unroll
        for (int rr = 0; rr < 4; rr++) {
            int row = by * 64 + i * 16 + (lane >> 4) * 4 + rr;
            if (row < cnt) {
                int node = lists[e * N_NODES + row];
                float tv = top_val[node];
                float* cp = out + (size_t)node * DIM + cbase;
                #pragma unroll
                for (int j = 0; j < 2; j++) {
                    float v = fmaxf(acc[i][j][rr] + bv[j], 0.f);
                    cp[j * 16] = v * tv;
                }
            }
        }
    }
}

extern "C" void kernel_launch(void* const* d_in, const int* in_sizes, int n_in,
                              void* d_out, int out_size, void* d_ws, size_t ws_size,
                              hipStream_t stream) {
    const float* x       = (const float*)d_in[0];
    const int*   edge    = (const int*)d_in[1];
    const float* gw      = (const float*)d_in[2];
    const float* gb      = (const float*)d_in[3];
    const float* w_self  = (const float*)d_in[4];
    const float* w_neigh = (const float*)d_in[5];
    const float* b_exp   = (const float*)d_in[6];
    float* out = (float*)d_out;

    char* p = (char*)d_ws;
    auto alloc = [&](size_t bytes) {
        char* r = p;
        p += (bytes + 255) & ~(size_t)255;
        return r;
    };
    bf16_t* Bt      = (bf16_t*)alloc((size_t)8 * DIM * K1 * 2);
    bf16_t* acat    = (bf16_t*)alloc((size_t)N_NODES * K1 * 2);
    bf16_t* h1      = (bf16_t*)alloc((size_t)NEXP * N_NODES * DIM * 2);
    int*    deg     = (int*)alloc((size_t)N_NODES * 4);
    int*    offs    = (int*)alloc((size_t)(N_NODES + 1) * 4);
    int*    cursor  = (int*)alloc((size_t)N_NODES * 4);
    int*    csr     = (int*)alloc((size_t)N_EDGES * 4);
    int*    top_idx = (int*)alloc((size_t)N_NODES * 4);
    float*  top_val = (float*)alloc((size_t)N_NODES * 4);
    int*    ecnt    = (int*)alloc(256);
    int*    lists   = (int*)alloc((size_t)NEXP * N_NODES * 4);

    const int* srcE = edge;
    const int* dstE = edge + N_EDGES;

    zero_kernel<<<40, 256, 0, stream>>>(deg, ecnt);
    gate_kernel<<<N_NODES / 4, 256, 0, stream>>>(x, gw, gb, top_idx, top_val, acat);
    bucket_kernel<<<40, 256, 0, stream>>>(top_idx, ecnt, lists);
    deg_kernel<<<N_EDGES / 256, 256, 0, stream>>>(dstE, deg);
    scan_kernel<<<1, 1024, 0, stream>>>(deg, offs, cursor);
    fill_kernel<<<N_EDGES / 256, 256, 0, stream>>>(srcE, dstE, cursor, csr);
    wtrans_kernel<<<dim3(16, 16, 16), dim3(32, 8), 0, stream>>>(w_neigh, w_self, Bt);
    agg1_kernel<<<N_NODES / 4, 256, 0, stream>>>(offs, csr, acat);
    gemm1_kernel<<<2560, 256, 0, stream>>>(acat, Bt, b_exp, h1);
    agg2_kernel<<<N_NODES / 4, 256, 0, stream>>>(offs, csr, top_idx, h1, acat);
    gemm2_kernel<<<dim3(4, 157, 4), 256, 0, stream>>>(acat, Bt, b_exp, out, lists, ecnt, top_val);
}

// Round 12
// 280.354 us; speedup vs baseline: 1.0720x; 1.0720x over previous
//
#include <hip/hip_runtime.h>
#include <hip/hip_bf16.h>
#include <cstdint>

#define N_NODES 10000
#define N_EDGES 160000
#define DIM 512
#define K1 1024
#define NEXP 4

typedef __bf16 bf16_t;
typedef bf16_t bf16x8 __attribute__((ext_vector_type(8)));
typedef float f32x4 __attribute__((ext_vector_type(4)));

#define AS1(p) ((__attribute__((address_space(1))) void*)(p))
#define AS3(p) ((__attribute__((address_space(3))) void*)(p))

// ---------------- zero counters ----------------
__global__ void zero_kernel(int* __restrict__ deg, int* __restrict__ ecnt) {
    int i = blockIdx.x * blockDim.x + threadIdx.x;
    if (i < N_NODES) deg[i] = 0;
    if (i < NEXP) ecnt[i] = 0;
}

// ---------------- gating + x->bf16 (no atomics) ----------------
__global__ void gate_kernel(const float* __restrict__ x,
                            const float* __restrict__ gw,
                            const float* __restrict__ gb,
                            int* __restrict__ top_idx,
                            float* __restrict__ top_val,
                            bf16_t* __restrict__ acat) {
    const int wave = threadIdx.x >> 6;
    const int lane = threadIdx.x & 63;
    const int node = blockIdx.x * 4 + wave;
    if (node >= N_NODES) return;
    const float4* x4 = (const float4*)(x + (size_t)node * DIM);
    const float4* gw4 = (const float4*)gw;
    float4 xa = x4[lane * 2];
    float4 xb = x4[lane * 2 + 1];
    float xv[8] = { xa.x, xa.y, xa.z, xa.w, xb.x, xb.y, xb.z, xb.w };
    float a0 = 0.f, a1 = 0.f, a2 = 0.f, a3 = 0.f;
    #pragma unroll
    for (int c = 0; c < 8; c++) {
        float4 g = gw4[lane * 8 + c];
        a0 += xv[c] * g.x; a1 += xv[c] * g.y; a2 += xv[c] * g.z; a3 += xv[c] * g.w;
    }
    bf16x8 o;
    #pragma unroll
    for (int c = 0; c < 8; c++) o[c] = (bf16_t)xv[c];
    *(bf16x8*)(acat + (size_t)node * K1 + DIM + lane * 8) = o;
    for (int off = 32; off > 0; off >>= 1) {
        a0 += __shfl_xor(a0, off);
        a1 += __shfl_xor(a1, off);
        a2 += __shfl_xor(a2, off);
        a3 += __shfl_xor(a3, off);
    }
    if (lane == 0) {
        float z[4] = { a0 + gb[0], a1 + gb[1], a2 + gb[2], a3 + gb[3] };
        int bi = 0; float bm = z[0];
        for (int e = 1; e < 4; e++) if (z[e] > bm) { bm = z[e]; bi = e; }
        float den = 0.f;
        for (int e = 0; e < 4; e++) den += expf(z[e] - bm);
        top_idx[node] = bi;
        top_val[node] = 1.0f / den;
    }
}

// ---------------- expert bucketing (stores within-expert rank) ----------------
__global__ void bucket_kernel(const int* __restrict__ top_idx,
                              int* __restrict__ ecnt,
                              int* __restrict__ lists,
                              int* __restrict__ grank) {
    __shared__ int lcnt[NEXP];
    __shared__ int base[NEXP];
    const int tid = threadIdx.x;
    if (tid < NEXP) lcnt[tid] = 0;
    __syncthreads();
    const int node = blockIdx.x * 256 + tid;
    int e = 0, rank = 0;
    if (node < N_NODES) {
        e = top_idx[node];
        rank = atomicAdd(&lcnt[e], 1);
    }
    __syncthreads();
    if (tid < NEXP) base[tid] = atomicAdd(&ecnt[tid], lcnt[tid]);
    __syncthreads();
    if (node < N_NODES) {
        int lr = base[e] + rank;            // within-expert rank
        lists[e * N_NODES + lr] = node;
        grank[node] = lr;
    }
}

// ---------------- CSR build ----------------
__global__ void deg_kernel(const int* __restrict__ dst, int* __restrict__ deg) {
    int i = blockIdx.x * blockDim.x + threadIdx.x;
    if (i < N_EDGES) atomicAdd(&deg[dst[i]], 1);
}

__global__ void scan_kernel(const int* __restrict__ deg,
                            int* __restrict__ offs,
                            int* __restrict__ cursor) {
    __shared__ int wsum[16];
    __shared__ int carrysh;
    const int tid = threadIdx.x;
    const int lane = tid & 63;
    const int wv = tid >> 6;
    if (tid == 0) carrysh = 0;
    __syncthreads();
    for (int base = 0; base < N_NODES; base += 1024) {
        int i = base + tid;
        int v = (i < N_NODES) ? deg[i] : 0;
        int s = v;
        #pragma unroll
        for (int off = 1; off < 64; off <<= 1) {
            int t = __shfl_up(s, off);
            if (lane >= off) s += t;
        }
        if (lane == 63) wsum[wv] = s;
        int carry = carrysh;
        __syncthreads();
        if (wv == 0) {
            int w = (lane < 16) ? wsum[lane] : 0;
            #pragma unroll
            for (int off = 1; off < 16; off <<= 1) {
                int t = __shfl_up(w, off);
                if (lane >= off) w += t;
            }
            if (lane < 16) wsum[lane] = w;
        }
        __syncthreads();
        int wbase = (wv > 0) ? wsum[wv - 1] : 0;
        int excl = carry + wbase + s - v;
        if (i < N_NODES) { offs[i] = excl; cursor[i] = excl; }
        int total = wsum[15];
        __syncthreads();
        if (tid == 0) carrysh = carry + total;
        __syncthreads();
    }
    if (tid == 0) offs[N_NODES] = carrysh;
}

__global__ void fill_kernel(const int* __restrict__ src, const int* __restrict__ dst,
                            int* __restrict__ cursor, int* __restrict__ csr) {
    int i = blockIdx.x * blockDim.x + threadIdx.x;
    if (i < N_EDGES) {
        int d = dst[i];
        int p = atomicAdd(&cursor[d], 1);
        csr[p] = src[i];
    }
}

// ---------------- weight convert+transpose ----------------
__global__ void wtrans_kernel(const float* __restrict__ w_neigh,
                              const float* __restrict__ w_self,
                              bf16_t* __restrict__ Bt) {
    __shared__ float tile[32][33];
    const int m = blockIdx.z;
    const bool isSelf = m >= 8;
    const int el = m & 7;
    const float* W = (isSelf ? w_self : w_neigh) + (size_t)el * DIM * DIM;
    const int k0 = blockIdx.x * 32;
    const int n0 = blockIdx.y * 32;
    const int tx = threadIdx.x, ty = threadIdx.y;
    for (int r = ty; r < 32; r += 8)
        tile[r][tx] = W[(size_t)(k0 + r) * DIM + n0 + tx];
    __syncthreads();
    for (int r = ty; r < 32; r += 8) {
        int n = n0 + r;
        int k = k0 + tx;
        Bt[((size_t)el * DIM + n) * K1 + (isSelf ? DIM : 0) + k] = (bf16_t)tile[tx][r];
    }
}

// ---------------- agg1: mean of x rows into acat cols 0..511, unroll 8 ----------------
__global__ void agg1_kernel(const int* __restrict__ offs, const int* __restrict__ csr,
                            bf16_t* __restrict__ acat) {
    const int wave = threadIdx.x >> 6;
    const int lane = threadIdx.x & 63;
    const int node = blockIdx.x * 4 + wave;
    if (node >= N_NODES) return;
    const int c0 = lane * 8;
    float s[8] = {0,0,0,0,0,0,0,0};
    int beg = offs[node];
    int end = offs[node + 1];
    int d = end - beg;
    int p = beg;
    for (; p + 8 <= end; p += 8) {
        bf16x8 v[8];
        #pragma unroll
        for (int q = 0; q < 8; q++) {
            int idx = csr[p + q];
            v[q] = *(const bf16x8*)(acat + (size_t)idx * K1 + DIM + c0);
        }
        #pragma unroll
        for (int q = 0; q < 8; q++)
            #pragma unroll
            for (int k = 0; k < 8; k++) s[k] += (float)v[q][k];
    }
    for (; p + 4 <= end; p += 4) {
        bf16x8 v[4];
        #pragma unroll
        for (int q = 0; q < 4; q++) {
            int idx = csr[p + q];
            v[q] = *(const bf16x8*)(acat + (size_t)idx * K1 + DIM + c0);
        }
        #pragma unroll
        for (int q = 0; q < 4; q++)
            #pragma unroll
            for (int k = 0; k < 8; k++) s[k] += (float)v[q][k];
    }
    for (; p < end; p++) {
        int idx = csr[p];
        bf16x8 v0 = *(const bf16x8*)(acat + (size_t)idx * K1 + DIM + c0);
        #pragma unroll
        for (int k = 0; k < 8; k++) s[k] += (float)v0[k];
    }
    float w = d > 0 ? 1.0f / (float)d : 0.0f;
    bf16x8 o;
    #pragma unroll
    for (int k = 0; k < 8; k++) o[k] = (bf16_t)(s[k] * w);
    *(bf16x8*)(acat + (size_t)node * K1 + c0) = o;
}

// ---------------- agg2: selected-expert mean + self copy -> COMPACTED row off[e]+rank ----------------
__global__ void agg2_kernel(const int* __restrict__ offs, const int* __restrict__ csr,
                            const int* __restrict__ top_idx,
                            const bf16_t* __restrict__ h1, bf16_t* __restrict__ acat,
                            const int* __restrict__ ecnt, const int* __restrict__ grank) {
    const int wave = threadIdx.x >> 6;
    const int lane = threadIdx.x & 63;
    const int node = blockIdx.x * 4 + wave;
    if (node >= N_NODES) return;
    const int c0 = lane * 8;
    const int e = top_idx[node];
    int off = 0;
    #pragma unroll
    for (int j = 0; j < NEXP; j++) if (j < e) off += ecnt[j];
    const int crow = off + grank[node];
    const bf16_t* hb = h1 + (size_t)e * N_NODES * DIM;
    float s[8] = {0,0,0,0,0,0,0,0};
    int beg = offs[node];
    int end = offs[node + 1];
    int d = end - beg;
    int p = beg;
    for (; p + 8 <= end; p += 8) {
        bf16x8 v[8];
        #pragma unroll
        for (int q = 0; q < 8; q++) {
            int idx = csr[p + q];
            v[q] = *(const bf16x8*)(hb + (size_t)idx * DIM + c0);
        }
        #pragma unroll
        for (int q = 0; q < 8; q++)
            #pragma unroll
            for (int k = 0; k < 8; k++) s[k] += (float)v[q][k];
    }
    for (; p + 4 <= end; p += 4) {
        bf16x8 v[4];
        #pragma unroll
        for (int q = 0; q < 4; q++) {
            int idx = csr[p + q];
            v[q] = *(const bf16x8*)(hb + (size_t)idx * DIM + c0);
        }
        #pragma unroll
        for (int q = 0; q < 4; q++)
            #pragma unroll
            for (int k = 0; k < 8; k++) s[k] += (float)v[q][k];
    }
    for (; p < end; p++) {
        int idx = csr[p];
        bf16x8 v0 = *(const bf16x8*)(hb + (size_t)idx * DIM + c0);
        #pragma unroll
        for (int k = 0; k < 8; k++) s[k] += (float)v0[k];
    }
    float w = d > 0 ? 1.0f / (float)d : 0.0f;
    bf16x8 o;
    #pragma unroll
    for (int k = 0; k < 8; k++) o[k] = (bf16_t)(s[k] * w);
    *(bf16x8*)(acat + (size_t)crow * K1 + c0) = o;
    *(bf16x8*)(acat + (size_t)crow * K1 + DIM + c0) = *(const bf16x8*)(hb + (size_t)node * DIM + c0);
}

// ---------------- GEMM layer 1: round-9 config (128x128, BK=32, swizzle, XCD-clustered) ----------------
__global__ __launch_bounds__(256)
void gemm1_kernel(const bf16_t* __restrict__ A,
                  const bf16_t* __restrict__ Bt,
                  const float* __restrict__ bias_all,
                  bf16_t* __restrict__ h1) {
    const int b = blockIdx.x;
    const int kq = b & 7;
    const int ke = kq >> 2;
    const int ky = kq & 3;
    const int r = b >> 3;
    const int yloc = r >> 3;
    const int xz = r & 7;
    const int bx = xz & 3;
    const int e = ke * 2 + (xz >> 2);
    const int by = ky * 20 + yloc;
    if (by >= 79) return;

    __shared__ __align__(16) bf16_t As[128 * 32];
    __shared__ __align__(16) bf16_t Bs[128 * 32];

    const int t = threadIdx.x;
    const int lane = t & 63;
    const int wave = t >> 6;
    const int wm = wave >> 1;
    const int wn = wave & 1;

    const int r0 = t >> 2;
    const int rot = (t >> 3) & 3;
    const int cgl = ((t & 3) - rot) & 3;

    int i0 = by * 128 + r0;
    int i1 = i0 + 64;
    int arow0 = min(i0, N_NODES - 1);
    int arow1 = min(i1, N_NODES - 1);

    const bf16_t* Bte = Bt + (size_t)(e * 2) * DIM * K1;   // layer 0
    const bf16_t* aptr0 = A + (size_t)arow0 * K1 + cgl * 8;
    const bf16_t* aptr1 = A + (size_t)arow1 * K1 + cgl * 8;
    const bf16_t* bptr0 = Bte + (size_t)(bx * 128 + r0) * K1 + cgl * 8;
    const bf16_t* bptr1 = bptr0 + (size_t)64 * K1;

    f32x4 acc[4][4] = {};
    char* asb = (char*)&As[0];
    char* bsb = (char*)&Bs[0];
    const int wb = wave * 1024;

    const int cpr = lane >> 4;
    const int rfr = lane & 15;

    for (int k0 = 0; k0 < K1; k0 += 32) {
        __syncthreads();
        __builtin_amdgcn_global_load_lds(AS1(aptr0), AS3(asb + wb),        16, 0, 0);
        __builtin_amdgcn_global_load_lds(AS1(aptr1), AS3(asb + 4096 + wb), 16, 0, 0);
        __builtin_amdgcn_global_load_lds(AS1(bptr0), AS3(bsb + wb),        16, 0, 0);
        __builtin_amdgcn_global_load_lds(AS1(bptr1), AS3(bsb + 4096 + wb), 16, 0, 0);
        __syncthreads();
        bf16x8 af[4], bfr[4];
        #pragma unroll
        for (int i = 0; i < 4; i++) {
            int rf = wm * 64 + i * 16 + rfr;
            int pp = (cpr + (rf >> 1)) & 3;
            af[i] = *(const bf16x8*)(As + rf * 32 + pp * 8);
        }
        #pragma unroll
        for (int j = 0; j < 4; j++) {
            int rf = wn * 64 + j * 16 + rfr;
            int pp = (cpr + (rf >> 1)) & 3;
            bfr[j] = *(const bf16x8*)(Bs + rf * 32 + pp * 8);
        }
        #pragma unroll
        for (int i = 0; i < 4; i++)
            #pragma unroll
            for (int j = 0; j < 4; j++)
                acc[i][j] = __builtin_amdgcn_mfma_f32_16x16x32_bf16(af[i], bfr[j], acc[i][j], 0, 0, 0);
        aptr0 += 32; aptr1 += 32; bptr0 += 32; bptr1 += 32;
    }

    const float* bias = bias_all + e * 1024;   // layer 0
    const int cbase = bx * 128 + wn * 64 + (lane & 15);
    float bv[4];
    #pragma unroll
    for (int j = 0; j < 4; j++) bv[j] = bias[cbase + j * 16];
    #pragma unroll
    for (int i = 0; i < 4; i++) {
        #pragma unroll
        for (int rr = 0; rr < 4; rr++) {
            int row = by * 128 + wm * 64 + i * 16 + (lane >> 4) * 4 + rr;
            if (row < N_NODES) {
                bf16_t* cp = h1 + ((size_t)e * N_NODES + row) * DIM + cbase;
                #pragma unroll
                for (int j = 0; j < 4; j++) {
                    float v = fmaxf(acc[i][j][rr] + bv[j], 0.f);
                    cp[j * 16] = (bf16_t)v;
                }
            }
        }
    }
}

// ---------------- GEMM layer 2: 64x128 tiles, CONTIGUOUS compacted A rows ----------------
// A rows live at [off[e], off[e]+cnt) in compact order; staging streams them like gemm1.
// Epilogue scatters to out via lists (once per element).
__global__ __launch_bounds__(256)
void gemm2_kernel(const bf16_t* __restrict__ A,
                  const bf16_t* __restrict__ Bt,
                  const float* __restrict__ bias_all,
                  float* __restrict__ out,
                  const int* __restrict__ lists,
                  const int* __restrict__ ecnt,
                  const float* __restrict__ top_val) {
    const int bx = blockIdx.x, by = blockIdx.y, e = blockIdx.z;
    const int cnt = ecnt[e];
    if (by * 64 >= cnt) return;
    int off = 0;
    #pragma unroll
    for (int j = 0; j < NEXP; j++) if (j < e) off += ecnt[j];

    __shared__ __align__(16) bf16_t As[64 * 32];
    __shared__ __align__(16) bf16_t Bs[128 * 32];

    const int t = threadIdx.x;
    const int lane = t & 63;
    const int wave = t >> 6;

    const int r0 = t >> 2;
    const int rot = (t >> 3) & 3;
    const int cgl = ((t & 3) - rot) & 3;

    int arow0 = off + min(by * 64 + r0, cnt - 1);

    const bf16_t* Bte = Bt + (size_t)(e * 2 + 1) * DIM * K1;   // layer 1
    const bf16_t* aptr0 = A + (size_t)arow0 * K1 + cgl * 8;
    const bf16_t* bptr0 = Bte + (size_t)(bx * 128 + r0) * K1 + cgl * 8;
    const bf16_t* bptr1 = bptr0 + (size_t)64 * K1;

    f32x4 acc[4][2] = {};
    char* asb = (char*)&As[0];
    char* bsb = (char*)&Bs[0];
    const int wb = wave * 1024;

    const int cpr = lane >> 4;
    const int rfr = lane & 15;

    for (int k0 = 0; k0 < K1; k0 += 32) {
        __syncthreads();
        __builtin_amdgcn_global_load_lds(AS1(aptr0), AS3(asb + wb),        16, 0, 0);
        __builtin_amdgcn_global_load_lds(AS1(bptr0), AS3(bsb + wb),        16, 0, 0);
        __builtin_amdgcn_global_load_lds(AS1(bptr1), AS3(bsb + 4096 + wb), 16, 0, 0);
        __syncthreads();
        bf16x8 af[4], bfr[2];
        #pragma unroll
        for (int i = 0; i < 4; i++) {
            int rf = i * 16 + rfr;
            int pp = (cpr + (rf >> 1)) & 3;
            af[i] = *(const bf16x8*)(As + rf * 32 + pp * 8);
        }
        #pragma unroll
        for (int j = 0; j < 2; j++) {
            int rf = wave * 32 + j * 16 + rfr;
            int pp = (cpr + (rf >> 1)) & 3;
            bfr[j] = *(const bf16x8*)(Bs + rf * 32 + pp * 8);
        }
        #pragma unroll
        for (int i = 0; i < 4; i++)
            #pragma unroll
            for (int j = 0; j < 2; j++)
                acc[i][j] = __builtin_amdgcn_mfma_f32_16x16x32_bf16(af[i], bfr[j], acc[i][j], 0, 0, 0);
        aptr0 += 32; bptr0 += 32; bptr1 += 32;
    }

    const float* bias = bias_all + e * 1024 + DIM;   // layer 1
    const int cbase = bx * 128 + wave * 32 + (lane & 15);
    float bv[2];
    #pragma unroll
    for (int j = 0; j < 2; j++) bv[j] = bias[cbase + j * 16];
    #pragma unroll
    for (int i = 0; i < 4; i++) {
        #pragma unroll
        for (int rr = 0; rr < 4; rr++) {
            int row = by * 64 + i * 16 + (lane >> 4) * 4 + rr;
            if (row < cnt) {
                int node = lists[e * N_NODES + row];
                float tv = top_val[node];
                float* cp = out + (size_t)node * DIM + cbase;
                #pragma unroll
                for (int j = 0; j < 2; j++) {
                    float v = fmaxf(acc[i][j][rr] + bv[j], 0.f);
                    cp[j * 16] = v * tv;
                }
            }
        }
    }
}

extern "C" void kernel_launch(void* const* d_in, const int* in_sizes, int n_in,
                              void* d_out, int out_size, void* d_ws, size_t ws_size,
                              hipStream_t stream) {
    const float* x       = (const float*)d_in[0];
    const int*   edge    = (const int*)d_in[1];
    const float* gw      = (const float*)d_in[2];
    const float* gb      = (const float*)d_in[3];
    const float* w_self  = (const float*)d_in[4];
    const float* w_neigh = (const float*)d_in[5];
    const float* b_exp   = (const float*)d_in[6];
    float* out = (float*)d_out;

    char* p = (char*)d_ws;
    auto alloc = [&](size_t bytes) {
        char* r = p;
        p += (bytes + 255) & ~(size_t)255;
        return r;
    };
    bf16_t* Bt      = (bf16_t*)alloc((size_t)8 * DIM * K1 * 2);
    bf16_t* acat    = (bf16_t*)alloc((size_t)N_NODES * K1 * 2);
    bf16_t* h1      = (bf16_t*)alloc((size_t)NEXP * N_NODES * DIM * 2);
    int*    deg     = (int*)alloc((size_t)N_NODES * 4);
    int*    offs    = (int*)alloc((size_t)(N_NODES + 1) * 4);
    int*    cursor  = (int*)alloc((size_t)N_NODES * 4);
    int*    csr     = (int*)alloc((size_t)N_EDGES * 4);
    int*    top_idx = (int*)alloc((size_t)N_NODES * 4);
    float*  top_val = (float*)alloc((size_t)N_NODES * 4);
    int*    ecnt    = (int*)alloc(256);
    int*    lists   = (int*)alloc((size_t)NEXP * N_NODES * 4);
    int*    grank   = (int*)alloc((size_t)N_NODES * 4);

    const int* srcE = edge;
    const int* dstE = edge + N_EDGES;

    zero_kernel<<<40, 256, 0, stream>>>(deg, ecnt);
    gate_kernel<<<N_NODES / 4, 256, 0, stream>>>(x, gw, gb, top_idx, top_val, acat);
    bucket_kernel<<<40, 256, 0, stream>>>(top_idx, ecnt, lists, grank);
    deg_kernel<<<N_EDGES / 256, 256, 0, stream>>>(dstE, deg);
    scan_kernel<<<1, 1024, 0, stream>>>(deg, offs, cursor);
    fill_kernel<<<N_EDGES / 256, 256, 0, stream>>>(srcE, dstE, cursor, csr);
    wtrans_kernel<<<dim3(16, 16, 16), dim3(32, 8), 0, stream>>>(w_neigh, w_self, Bt);
    agg1_kernel<<<N_NODES / 4, 256, 0, stream>>>(offs, csr, acat);
    gemm1_kernel<<<1280, 256, 0, stream>>>(acat, Bt, b_exp, h1);
    agg2_kernel<<<N_NODES / 4, 256, 0, stream>>>(offs, csr, top_idx, h1, acat, ecnt, grank);
    gemm2_kernel<<<dim3(4, 157, 4), 256, 0, stream>>>(acat, Bt, b_exp, out, lists, ecnt, top_val);
}